// Round 1
// baseline (592.833 us; speedup 1.0000x reference)
//
#include <hip/hip_runtime.h>
#include <math.h>

// ---------------- weight transpose: w[co][ci][kh][kw] -> wt[ci][kh][kw][co] -----------
__global__ void kprep(const float* __restrict__ w2, const float* __restrict__ w3,
                      const float* __restrict__ w4, float* __restrict__ w2t,
                      float* __restrict__ w3t, float* __restrict__ w4t) {
  int i = blockIdx.x * 256 + threadIdx.x;
  if (i < 52500) {            // w2,w4: 50*50*3*7, r = ci*21+di*7+dj in 0..1049
    int co = i % 50, r = i / 50;
    w2t[i] = w2[co * 1050 + r];
    w4t[i] = w4[co * 1050 + r];
  } else {
    int j = i - 52500;
    if (j < 37500) {          // w3: 50*50*3*5, r in 0..749
      int co = j % 50, r = j / 50;
      w3t[j] = w3[co * 750 + r];
    }
  }
}

// ---------------- K1: conv1 (1->50ci, 3x7 circular, 64x256) + maxpool 2x4 + relu -----
__global__ __launch_bounds__(256) void k1(const float* __restrict__ x,
                                          const float* __restrict__ w1,
                                          const float* __restrict__ b1,
                                          float* __restrict__ a1) {
  int bid = blockIdx.x;            // 256 blocks
  int b = bid >> 3;                // image 0..31
  int pr0 = (bid & 7) * 4;         // pooled-row group
  int ty = threadIdx.x >> 6;       // 0..3
  int pc = threadIdx.x & 63;       // pooled col 0..63
  int pr = pr0 + ty;
  const float* xb = x + b * (64 * 256);
  // register window: rows 2pr-2..2pr+1, cols 4pc-6..4pc+3 (circular)
  float xw[4][10];
#pragma unroll
  for (int r = 0; r < 4; ++r) {
    int row = (2 * pr - 2 + r) & 63;
#pragma unroll
    for (int c = 0; c < 10; ++c) {
      int col = (4 * pc - 6 + c) & 255;
      xw[r][c] = xb[row * 256 + col];
    }
  }
  for (int co = 0; co < 50; ++co) {
    const float* wp = w1 + co * 21;      // wave-uniform -> scalar loads
    float m = -1e30f;
#pragma unroll
    for (int iy = 0; iy < 2; ++iy) {
#pragma unroll
      for (int jx = 0; jx < 4; ++jx) {
        float s = 0.f;
#pragma unroll
        for (int di = 0; di < 3; ++di)
#pragma unroll
          for (int dj = 0; dj < 7; ++dj)
            s = fmaf(xw[iy + 2 - di][jx + 6 - dj], wp[di * 7 + dj], s);
        m = fmaxf(m, s);
      }
    }
    float v = fmaxf(m + b1[co], 0.f);
    a1[((b * 50 + co) * 32 + pr) * 64 + pc] = v;
  }
}

// ---------------- K2: conv2 (50->50, 3x7 circular, 32x64) + maxpool 2x4 + relu -------
__global__ __launch_bounds__(256) void k2(const float* __restrict__ a1,
                                          const float* __restrict__ w2t,
                                          const float* __restrict__ b2,
                                          float* __restrict__ a2) {
  __shared__ float sm[3840];       // staging 10*6*64, pool reuse 10*4*64
  int bid = blockIdx.x;            // 256 blocks
  int b = bid >> 3;
  int r0 = (bid & 7) * 4;          // pre-pool rows r0..r0+3
  int y = threadIdx.x >> 6;        // 0..3
  int xcol = threadIdx.x & 63;
  float acc[50];
#pragma unroll
  for (int co = 0; co < 50; ++co) acc[co] = b2[co];
  const float* ain = a1 + b * (50 * 2048);
  for (int cc = 0; cc < 5; ++cc) {            // ci chunks of 10
    __syncthreads();
    for (int e = threadIdx.x; e < 3840; e += 256) {   // [ci][rr(6)][col(64)]
      int ci = e / 384;
      int rr = (e >> 6) % 6;
      int col = e & 63;
      int row = (r0 - 2 + rr) & 31;
      sm[e] = ain[(cc * 10 + ci) * 2048 + row * 64 + col];
    }
    __syncthreads();
    for (int ci = 0; ci < 10; ++ci) {
      const float* sin_ = sm + ci * 384;
      const float* wbase = w2t + (cc * 10 + ci) * 21 * 50;
#pragma unroll
      for (int di = 0; di < 3; ++di) {
        const float* srow = sin_ + (y + 2 - di) * 64;
#pragma unroll
        for (int dj = 0; dj < 7; ++dj) {
          float xv = srow[(xcol - dj) & 63];
          const float* wrow = wbase + (di * 7 + dj) * 50;  // wave-uniform
#pragma unroll
          for (int co = 0; co < 50; ++co)
            acc[co] = fmaf(xv, wrow[co], acc[co]);
        }
      }
    }
  }
  // pool 2x4 + relu, co chunks of 10 through LDS
#pragma unroll
  for (int cc = 0; cc < 5; ++cc) {
    __syncthreads();
#pragma unroll
    for (int k = 0; k < 10; ++k)
      sm[k * 256 + y * 64 + xcol] = acc[cc * 10 + k];
    __syncthreads();
    for (int w = threadIdx.x; w < 320; w += 256) {
      int cop = w / 32;
      int pr = (w >> 4) & 1;
      int pc = w & 15;
      float m = -1e30f;
#pragma unroll
      for (int yy = 0; yy < 2; ++yy)
#pragma unroll
        for (int xx = 0; xx < 4; ++xx)
          m = fmaxf(m, sm[cop * 256 + (pr * 2 + yy) * 64 + pc * 4 + xx]);
      m = fmaxf(m, 0.f);
      a2[((b * 50 + cc * 10 + cop) * 16 + (r0 >> 1) + pr) * 16 + pc] = m;
    }
  }
}

// ---------------- K3: combine(even + mean(odd)) -> upsample(2,4)-sparse conv3 (3x5) + relu
__global__ __launch_bounds__(512) void k3(const float* __restrict__ a2,
                                          const float* __restrict__ w3t,
                                          const float* __restrict__ b3,
                                          float* __restrict__ a3) {
  __shared__ float ts[4000];     // [ci(50)][rr(5)][tc(16)]
  __shared__ float mean_s[64];
  __shared__ float part[200];
  int bid = blockIdx.x;          // 64 blocks
  int b = bid >> 2;
  int r0 = (bid & 3) * 8;        // output rows r0..r0+7
  int tid = threadIdx.x;
  const float* aodd = a2 + (2 * b + 1) * (50 * 256);
  if (tid < 200) {
    int ci = tid >> 2, p = tid & 3;
    float s = 0.f;
    for (int k = 0; k < 64; ++k) s += aodd[ci * 256 + p * 64 + k];
    part[tid] = s;
  }
  __syncthreads();
  if (tid < 50)
    mean_s[tid] = (part[4 * tid] + part[4 * tid + 1] + part[4 * tid + 2] + part[4 * tid + 3]) * (1.f / 256.f);
  __syncthreads();
  const float* aev = a2 + (2 * b) * (50 * 256);
  for (int e = tid; e < 4000; e += 512) {
    int ci = e / 80;
    int rr = (e >> 4) % 5;
    int tc = e & 15;
    int trow = ((r0 >> 1) - 1 + rr) & 15;
    ts[e] = aev[ci * 256 + trow * 16 + tc] + mean_s[ci];
  }
  __syncthreads();
  int wv = __builtin_amdgcn_readfirstlane(tid >> 6);   // 0..7, force SGPR
  int lane = tid & 63;
  int p = wv >> 2;               // row parity class
  int m = wv & 3;                // j%4 class
  int q = lane & 15;
  int yidx = lane >> 4;          // 0..3
  int i = r0 + 2 * yidx + p;
  int j = 4 * q + m;
  float acc[50];
#pragma unroll
  for (int co = 0; co < 50; ++co) acc[co] = b3[co];
  int ndi = (p == 0) ? 2 : 1;    // even rows: di in {0,2}; odd: {1}
  int ndj = (m == 0) ? 2 : 1;    // kw=5: m==0 -> dj in {0,4}; else {m}
  for (int aa = 0; aa < ndi; ++aa) {
    int di = (p == 0) ? (2 * aa) : 1;
    int rr = 1 + ((2 * yidx + p - di) >> 1);
    for (int e2 = 0; e2 < ndj; ++e2) {
      int dj = (m == 0) ? (4 * e2) : m;
      int tc = ((j - dj + 64) >> 2) & 15;
      for (int ci = 0; ci < 50; ++ci) {
        float xv = ts[ci * 80 + rr * 16 + tc];
        const float* wrow = w3t + (ci * 15 + di * 5 + dj) * 50;  // wave-uniform
#pragma unroll
        for (int co = 0; co < 50; ++co)
          acc[co] = fmaf(xv, wrow[co], acc[co]);
      }
    }
  }
  float* aout = a3 + b * (50 * 2048);
#pragma unroll
  for (int co = 0; co < 50; ++co)
    aout[co * 2048 + i * 64 + j] = fmaxf(acc[co], 0.f);
}

// ---------------- K4: upsample(2,4)-sparse conv4 (3x7, 64x256) + relu ----------------
__global__ __launch_bounds__(512) void k4(const float* __restrict__ a3,
                                          const float* __restrict__ w4t,
                                          const float* __restrict__ b4,
                                          float* __restrict__ a4) {
  __shared__ float s4[6400];     // [ci(50)][rr(2)][col(64)]
  int bid = blockIdx.x;          // 512 blocks
  int b = bid >> 5;
  int r0 = (bid & 31) * 2;       // output rows r0, r0+1
  int tid = threadIdx.x;
  const float* ain = a3 + b * (50 * 2048);
  for (int e = tid; e < 6400; e += 512) {
    int ci = e >> 7;
    int rr = (e >> 6) & 1;
    int col = e & 63;
    int row = ((r0 >> 1) - 1 + rr) & 31;
    s4[e] = ain[ci * 2048 + row * 64 + col];
  }
  __syncthreads();
  int wv = __builtin_amdgcn_readfirstlane(tid >> 6);  // 0..7
  int lane = tid & 63;
  int rowsel = wv >> 2;
  int m = wv & 3;
  int i = r0 + rowsel;
  int j = 4 * lane + m;
  float acc[50];
#pragma unroll
  for (int co = 0; co < 50; ++co) acc[co] = b4[co];
  int ndi = (rowsel == 0) ? 2 : 1;
  int ndj = (m < 3) ? 2 : 1;     // kw=7: dj in {m, m+4} when m<3
  for (int aa = 0; aa < ndi; ++aa) {
    int di = (rowsel == 0) ? (2 * aa) : 1;
    int rr = 1 - (di >> 1);
    for (int e2 = 0; e2 < ndj; ++e2) {
      int dj = m + 4 * e2;
      int tc = ((j - dj) >> 2) & 63;   // j-dj is multiple of 4
      for (int ci = 0; ci < 50; ++ci) {
        float xv = s4[ci * 128 + rr * 64 + tc];
        const float* wrow = w4t + (ci * 21 + di * 7 + dj) * 50;  // wave-uniform
#pragma unroll
        for (int co = 0; co < 50; ++co)
          acc[co] = fmaf(xv, wrow[co], acc[co]);
      }
    }
  }
  float* aout = a4 + b * (50 * 16384);
#pragma unroll
  for (int co = 0; co < 50; ++co)
    aout[co * 16384 + i * 256 + j] = fmaxf(acc[co], 0.f);
}

// ---------------- K5: conv5 (50->1, 3x7 circular, 64x256) + sigmoid ------------------
__global__ __launch_bounds__(256) void k5(const float* __restrict__ a4,
                                          const float* __restrict__ w5,
                                          const float* __restrict__ b5,
                                          float* __restrict__ out) {
  __shared__ __align__(16) float s5[7920];   // [ci(5)][rr(6)][c(264)], c-8 = actual col
  int bid = blockIdx.x;          // 256 blocks
  int b = bid >> 4;
  int r0 = (bid & 15) * 4;
  int tid = threadIdx.x;
  int y = tid >> 6;              // row 0..3
  int q = tid & 63;
  int j0 = q * 4;
  float acc0 = b5[0], acc1 = b5[0], acc2 = b5[0], acc3 = b5[0];
  const float* ain = a4 + b * (50 * 16384);
  for (int cc = 0; cc < 10; ++cc) {          // ci chunks of 5
    __syncthreads();
    for (int e = tid; e < 7920; e += 256) {
      int ci = e / 1584;
      int rr = (e / 264) % 6;
      int c = e % 264;
      int row = (r0 - 2 + rr) & 63;
      int col = (c - 8) & 255;
      s5[e] = ain[(cc * 5 + ci) * 16384 + row * 256 + col];
    }
    __syncthreads();
#pragma unroll
    for (int ci = 0; ci < 5; ++ci) {
#pragma unroll
      for (int di = 0; di < 3; ++di) {
        const float4* prow = (const float4*)&s5[ci * 1584 + (y + 2 - di) * 264 + j0];
        float4 v0 = prow[0], v1 = prow[1], v2 = prow[2];
        float wnd[12] = {v0.x, v0.y, v0.z, v0.w, v1.x, v1.y, v1.z, v1.w,
                         v2.x, v2.y, v2.z, v2.w};
        const float* wp = w5 + ((cc * 5 + ci) * 3 + di) * 7;   // wave-uniform
#pragma unroll
        for (int dj = 0; dj < 7; ++dj) {
          float wgt = wp[dj];
          acc0 = fmaf(wnd[8 - dj], wgt, acc0);
          acc1 = fmaf(wnd[9 - dj], wgt, acc1);
          acc2 = fmaf(wnd[10 - dj], wgt, acc2);
          acc3 = fmaf(wnd[11 - dj], wgt, acc3);
        }
      }
    }
  }
  float4 r;
  r.x = 1.f / (1.f + expf(-acc0));
  r.y = 1.f / (1.f + expf(-acc1));
  r.z = 1.f / (1.f + expf(-acc2));
  r.w = 1.f / (1.f + expf(-acc3));
  *(float4*)(out + b * 16384 + (r0 + y) * 256 + j0) = r;
}

extern "C" void kernel_launch(void* const* d_in, const int* in_sizes, int n_in,
                              void* d_out, int out_size, void* d_ws, size_t ws_size,
                              hipStream_t stream) {
  (void)in_sizes; (void)n_in; (void)out_size; (void)ws_size;
  const float* x  = (const float*)d_in[0];
  const float* w1 = (const float*)d_in[1];
  const float* b1 = (const float*)d_in[2];
  const float* w2 = (const float*)d_in[3];
  const float* b2 = (const float*)d_in[4];
  const float* w3 = (const float*)d_in[5];
  const float* b3 = (const float*)d_in[6];
  const float* w4 = (const float*)d_in[7];
  const float* b4 = (const float*)d_in[8];
  const float* w5 = (const float*)d_in[9];
  const float* b5 = (const float*)d_in[10];
  float* out = (float*)d_out;
  float* ws  = (float*)d_ws;
  float* w2t = ws;                       // 52500
  float* w3t = w2t + 52500;              // 37500
  float* w4t = w3t + 37500;              // 52500
  float* a1  = w4t + 52500;              // 32*50*32*64  = 3,276,800
  float* a2  = a1 + 32 * 50 * 32 * 64;   // 32*50*16*16  = 409,600
  float* a3  = a2 + 32 * 50 * 16 * 16;   // 16*50*32*64  = 1,638,400
  float* a4  = a3 + 16 * 50 * 32 * 64;   // 16*50*64*256 = 13,107,200
  hipLaunchKernelGGL(kprep, dim3(352), dim3(256), 0, stream, w2, w3, w4, w2t, w3t, w4t);
  hipLaunchKernelGGL(k1, dim3(256), dim3(256), 0, stream, x, w1, b1, a1);
  hipLaunchKernelGGL(k2, dim3(256), dim3(256), 0, stream, a1, w2t, b2, a2);
  hipLaunchKernelGGL(k3, dim3(64),  dim3(512), 0, stream, a2, w3t, b3, a3);
  hipLaunchKernelGGL(k4, dim3(512), dim3(512), 0, stream, a3, w4t, b4, a4);
  hipLaunchKernelGGL(k5, dim3(256), dim3(256), 0, stream, a4, w5, b5, out);
}

// Round 2
// 368.631 us; speedup vs baseline: 1.6082x; 1.6082x over previous
//
#include <hip/hip_runtime.h>
#include <math.h>

// ---------------- weight transpose: w[co][ci][kh][kw] -> wt[ci][kh][kw][co] -----------
__global__ void kprep(const float* __restrict__ w2, const float* __restrict__ w3,
                      const float* __restrict__ w4, float* __restrict__ w2t,
                      float* __restrict__ w3t, float* __restrict__ w4t) {
  int i = blockIdx.x * 256 + threadIdx.x;
  if (i < 52500) {            // w2,w4: 50*50*3*7, r = ci*21+di*7+dj in 0..1049
    int co = i % 50, r = i / 50;
    w2t[i] = w2[co * 1050 + r];
    w4t[i] = w4[co * 1050 + r];
  } else {
    int j = i - 52500;
    if (j < 37500) {          // w3: 50*50*3*5, r in 0..749
      int co = j % 50, r = j / 50;
      w3t[j] = w3[co * 750 + r];
    }
  }
}

// ---------------- K1: conv1 (1ci->50co, 3x7 circular, 64x256) + maxpool 2x4 + relu ---
// grid (8 rowgrp, 5 cochunk, 32 img) x 256 thr. acc over 10 co -> no spill.
__global__ __launch_bounds__(256) void k1(const float* __restrict__ x,
                                          const float* __restrict__ w1,
                                          const float* __restrict__ b1,
                                          float* __restrict__ a1) {
  int b = blockIdx.z;
  int pr0 = blockIdx.x * 4;
  int co0 = blockIdx.y * 10;
  int ty = threadIdx.x >> 6;       // 0..3
  int pc = threadIdx.x & 63;       // pooled col 0..63
  int pr = pr0 + ty;
  const float* xb = x + b * (64 * 256);
  float xw[4][10];
#pragma unroll
  for (int r = 0; r < 4; ++r) {
    int row = (2 * pr - 2 + r) & 63;
#pragma unroll
    for (int c = 0; c < 10; ++c) {
      int col = (4 * pc - 6 + c) & 255;
      xw[r][c] = xb[row * 256 + col];
    }
  }
#pragma unroll
  for (int cq = 0; cq < 10; ++cq) {
    int co = co0 + cq;
    const float* wp = w1 + co * 21;      // wave-uniform -> scalar loads
    float m = -1e30f;
#pragma unroll
    for (int iy = 0; iy < 2; ++iy) {
#pragma unroll
      for (int jx = 0; jx < 4; ++jx) {
        float s = 0.f;
#pragma unroll
        for (int di = 0; di < 3; ++di)
#pragma unroll
          for (int dj = 0; dj < 7; ++dj)
            s = fmaf(xw[iy + 2 - di][jx + 6 - dj], wp[di * 7 + dj], s);
        m = fmaxf(m, s);
      }
    }
    float v = fmaxf(m + b1[co], 0.f);
    a1[((b * 50 + co) * 32 + pr) * 64 + pc] = v;
  }
}

// ---------------- K2: conv2 (50->50, 3x7 circular, 32x64) + maxpool 2x4 + relu -------
// grid (8 rowgrp, 5 cochunk, 32 img) x 256 thr. acc[10] in regs.
__global__ __launch_bounds__(256) void k2(const float* __restrict__ a1,
                                          const float* __restrict__ w2t,
                                          const float* __restrict__ b2,
                                          float* __restrict__ a2) {
  __shared__ float sm[3840];       // staging 10*6*64, pool reuse 10*4*64
  int b = blockIdx.z;
  int r0 = blockIdx.x * 4;         // pre-pool rows r0..r0+3
  int cc = blockIdx.y;             // co chunk
  int co0 = cc * 10;
  int y = threadIdx.x >> 6;        // 0..3
  int xcol = threadIdx.x & 63;
  float acc[10];
#pragma unroll
  for (int co = 0; co < 10; ++co) acc[co] = b2[co0 + co];
  const float* ain = a1 + b * (50 * 2048);
  for (int cci = 0; cci < 5; ++cci) {         // ci chunks of 10
    __syncthreads();
    for (int e = threadIdx.x; e < 3840; e += 256) {   // [ci][rr(6)][col(64)]
      int ci = e / 384;
      int rr = (e >> 6) % 6;
      int col = e & 63;
      int row = (r0 - 2 + rr) & 31;
      sm[e] = ain[(cci * 10 + ci) * 2048 + row * 64 + col];
    }
    __syncthreads();
    for (int ci = 0; ci < 10; ++ci) {
      const float* sin_ = sm + ci * 384;
      const float* wbase = w2t + (cci * 10 + ci) * 21 * 50 + co0;
#pragma unroll
      for (int di = 0; di < 3; ++di) {
        const float* srow = sin_ + (y + 2 - di) * 64;
#pragma unroll
        for (int dj = 0; dj < 7; ++dj) {
          float xv = srow[(xcol - dj) & 63];
          const float* wrow = wbase + (di * 7 + dj) * 50;  // wave-uniform
#pragma unroll
          for (int co = 0; co < 10; ++co)
            acc[co] = fmaf(xv, wrow[co], acc[co]);
        }
      }
    }
  }
  // pool 2x4 + relu through LDS
  __syncthreads();
#pragma unroll
  for (int k = 0; k < 10; ++k)
    sm[k * 256 + y * 64 + xcol] = acc[k];
  __syncthreads();
  for (int w = threadIdx.x; w < 320; w += 256) {
    int cop = w / 32;
    int pr = (w >> 4) & 1;
    int pc = w & 15;
    float m = -1e30f;
#pragma unroll
    for (int yy = 0; yy < 2; ++yy)
#pragma unroll
      for (int xx = 0; xx < 4; ++xx)
        m = fmaxf(m, sm[cop * 256 + (pr * 2 + yy) * 64 + pc * 4 + xx]);
    m = fmaxf(m, 0.f);
    a2[((b * 50 + co0 + cop) * 16 + (r0 >> 1) + pr) * 16 + pc] = m;
  }
}

// ---------------- K3: combine(even + mean(odd)) -> upsample(2,4)-sparse conv3 (3x5) + relu
// grid (4 rowgrp, 5 cochunk, 16 img) x 512 thr. acc[10].
__global__ __launch_bounds__(512) void k3(const float* __restrict__ a2,
                                          const float* __restrict__ w3t,
                                          const float* __restrict__ b3,
                                          float* __restrict__ a3) {
  __shared__ float ts[4000];     // [ci(50)][rr(5)][tc(16)]
  __shared__ float mean_s[64];
  __shared__ float part[200];
  int b = blockIdx.z;
  int r0 = blockIdx.x * 8;       // output rows r0..r0+7
  int co0 = blockIdx.y * 10;
  int tid = threadIdx.x;
  const float* aodd = a2 + (2 * b + 1) * (50 * 256);
  if (tid < 200) {
    int ci = tid >> 2, p = tid & 3;
    float s = 0.f;
    for (int k = 0; k < 64; ++k) s += aodd[ci * 256 + p * 64 + k];
    part[tid] = s;
  }
  __syncthreads();
  if (tid < 50)
    mean_s[tid] = (part[4 * tid] + part[4 * tid + 1] + part[4 * tid + 2] + part[4 * tid + 3]) * (1.f / 256.f);
  __syncthreads();
  const float* aev = a2 + (2 * b) * (50 * 256);
  for (int e = tid; e < 4000; e += 512) {
    int ci = e / 80;
    int rr = (e >> 4) % 5;
    int tc = e & 15;
    int trow = ((r0 >> 1) - 1 + rr) & 15;
    ts[e] = aev[ci * 256 + trow * 16 + tc] + mean_s[ci];
  }
  __syncthreads();
  int wv = __builtin_amdgcn_readfirstlane(tid >> 6);   // 0..7, force SGPR
  int lane = tid & 63;
  int p = wv >> 2;               // row parity class
  int m = wv & 3;                // j%4 class
  int q = lane & 15;
  int yidx = lane >> 4;          // 0..3
  int i = r0 + 2 * yidx + p;
  int j = 4 * q + m;
  float acc[10];
#pragma unroll
  for (int co = 0; co < 10; ++co) acc[co] = b3[co0 + co];
  int ndi = (p == 0) ? 2 : 1;    // even rows: di in {0,2}; odd: {1}
  int ndj = (m == 0) ? 2 : 1;    // kw=5: m==0 -> dj in {0,4}; else {m}
  for (int aa = 0; aa < ndi; ++aa) {
    int di = (p == 0) ? (2 * aa) : 1;
    int rr = 1 + ((2 * yidx + p - di) >> 1);
    for (int e2 = 0; e2 < ndj; ++e2) {
      int dj = (m == 0) ? (4 * e2) : m;
      int tc = ((j - dj + 64) >> 2) & 15;
      for (int ci = 0; ci < 50; ++ci) {
        float xv = ts[ci * 80 + rr * 16 + tc];
        const float* wrow = w3t + (ci * 15 + di * 5 + dj) * 50 + co0;  // wave-uniform
#pragma unroll
        for (int co = 0; co < 10; ++co)
          acc[co] = fmaf(xv, wrow[co], acc[co]);
      }
    }
  }
  float* aout = a3 + b * (50 * 2048);
#pragma unroll
  for (int co = 0; co < 10; ++co)
    aout[(co0 + co) * 2048 + i * 64 + j] = fmaxf(acc[co], 0.f);
}

// ---------------- K4: upsample(2,4)-sparse conv4 (3x7, 64x256) + relu ----------------
// grid (32 rowgrp, 5 cochunk, 16 img) x 512 thr. acc[10].
__global__ __launch_bounds__(512) void k4(const float* __restrict__ a3,
                                          const float* __restrict__ w4t,
                                          const float* __restrict__ b4,
                                          float* __restrict__ a4) {
  __shared__ float s4[6400];     // [ci(50)][rr(2)][col(64)]
  int b = blockIdx.z;
  int r0 = blockIdx.x * 2;       // output rows r0, r0+1
  int co0 = blockIdx.y * 10;
  int tid = threadIdx.x;
  const float* ain = a3 + b * (50 * 2048);
  for (int e = tid; e < 6400; e += 512) {
    int ci = e >> 7;
    int rr = (e >> 6) & 1;
    int col = e & 63;
    int row = ((r0 >> 1) - 1 + rr) & 31;
    s4[e] = ain[ci * 2048 + row * 64 + col];
  }
  __syncthreads();
  int wv = __builtin_amdgcn_readfirstlane(tid >> 6);  // 0..7
  int lane = tid & 63;
  int rowsel = wv >> 2;
  int m = wv & 3;
  int i = r0 + rowsel;
  int j = 4 * lane + m;
  float acc[10];
#pragma unroll
  for (int co = 0; co < 10; ++co) acc[co] = b4[co0 + co];
  int ndi = (rowsel == 0) ? 2 : 1;
  int ndj = (m < 3) ? 2 : 1;     // kw=7: dj in {m, m+4} when m<3
  for (int aa = 0; aa < ndi; ++aa) {
    int di = (rowsel == 0) ? (2 * aa) : 1;
    int rr = 1 - (di >> 1);
    for (int e2 = 0; e2 < ndj; ++e2) {
      int dj = m + 4 * e2;
      int tc = ((j - dj) >> 2) & 63;   // j-dj is multiple of 4
      for (int ci = 0; ci < 50; ++ci) {
        float xv = s4[ci * 128 + rr * 64 + tc];
        const float* wrow = w4t + (ci * 21 + di * 7 + dj) * 50 + co0;  // wave-uniform
#pragma unroll
        for (int co = 0; co < 10; ++co)
          acc[co] = fmaf(xv, wrow[co], acc[co]);
      }
    }
  }
  float* aout = a4 + b * (50 * 16384);
#pragma unroll
  for (int co = 0; co < 10; ++co)
    aout[(co0 + co) * 16384 + i * 256 + j] = fmaxf(acc[co], 0.f);
}

// ---------------- K5: conv5 (50->1, 3x7 circular, 64x256) + sigmoid ------------------
__global__ __launch_bounds__(256) void k5(const float* __restrict__ a4,
                                          const float* __restrict__ w5,
                                          const float* __restrict__ b5,
                                          float* __restrict__ out) {
  __shared__ __align__(16) float s5[7920];   // [ci(5)][rr(6)][c(264)], c-8 = actual col
  int bid = blockIdx.x;          // 256 blocks
  int b = bid >> 4;
  int r0 = (bid & 15) * 4;
  int tid = threadIdx.x;
  int y = tid >> 6;              // row 0..3
  int q = tid & 63;
  int j0 = q * 4;
  float acc0 = b5[0], acc1 = b5[0], acc2 = b5[0], acc3 = b5[0];
  const float* ain = a4 + b * (50 * 16384);
  for (int cc = 0; cc < 10; ++cc) {          // ci chunks of 5
    __syncthreads();
    for (int e = tid; e < 7920; e += 256) {
      int ci = e / 1584;
      int rr = (e / 264) % 6;
      int c = e % 264;
      int row = (r0 - 2 + rr) & 63;
      int col = (c - 8) & 255;
      s5[e] = ain[(cc * 5 + ci) * 16384 + row * 256 + col];
    }
    __syncthreads();
#pragma unroll
    for (int ci = 0; ci < 5; ++ci) {
#pragma unroll
      for (int di = 0; di < 3; ++di) {
        const float4* prow = (const float4*)&s5[ci * 1584 + (y + 2 - di) * 264 + j0];
        float4 v0 = prow[0], v1 = prow[1], v2 = prow[2];
        float wnd[12] = {v0.x, v0.y, v0.z, v0.w, v1.x, v1.y, v1.z, v1.w,
                         v2.x, v2.y, v2.z, v2.w};
        const float* wp = w5 + ((cc * 5 + ci) * 3 + di) * 7;   // wave-uniform
#pragma unroll
        for (int dj = 0; dj < 7; ++dj) {
          float wgt = wp[dj];
          acc0 = fmaf(wnd[8 - dj], wgt, acc0);
          acc1 = fmaf(wnd[9 - dj], wgt, acc1);
          acc2 = fmaf(wnd[10 - dj], wgt, acc2);
          acc3 = fmaf(wnd[11 - dj], wgt, acc3);
        }
      }
    }
  }
  float4 r;
  r.x = 1.f / (1.f + expf(-acc0));
  r.y = 1.f / (1.f + expf(-acc1));
  r.z = 1.f / (1.f + expf(-acc2));
  r.w = 1.f / (1.f + expf(-acc3));
  *(float4*)(out + b * 16384 + (r0 + y) * 256 + j0) = r;
}

extern "C" void kernel_launch(void* const* d_in, const int* in_sizes, int n_in,
                              void* d_out, int out_size, void* d_ws, size_t ws_size,
                              hipStream_t stream) {
  (void)in_sizes; (void)n_in; (void)out_size; (void)ws_size;
  const float* x  = (const float*)d_in[0];
  const float* w1 = (const float*)d_in[1];
  const float* b1 = (const float*)d_in[2];
  const float* w2 = (const float*)d_in[3];
  const float* b2 = (const float*)d_in[4];
  const float* w3 = (const float*)d_in[5];
  const float* b3 = (const float*)d_in[6];
  const float* w4 = (const float*)d_in[7];
  const float* b4 = (const float*)d_in[8];
  const float* w5 = (const float*)d_in[9];
  const float* b5 = (const float*)d_in[10];
  float* out = (float*)d_out;
  float* ws  = (float*)d_ws;
  float* w2t = ws;                       // 52500
  float* w3t = w2t + 52500;              // 37500
  float* w4t = w3t + 37500;              // 52500
  float* a1  = w4t + 52500;              // 32*50*32*64  = 3,276,800
  float* a2  = a1 + 32 * 50 * 32 * 64;   // 32*50*16*16  = 409,600
  float* a3  = a2 + 32 * 50 * 16 * 16;   // 16*50*32*64  = 1,638,400
  float* a4  = a3 + 16 * 50 * 32 * 64;   // 16*50*64*256 = 13,107,200
  hipLaunchKernelGGL(kprep, dim3(352), dim3(256), 0, stream, w2, w3, w4, w2t, w3t, w4t);
  hipLaunchKernelGGL(k1, dim3(8, 5, 32), dim3(256), 0, stream, x, w1, b1, a1);
  hipLaunchKernelGGL(k2, dim3(8, 5, 32), dim3(256), 0, stream, a1, w2t, b2, a2);
  hipLaunchKernelGGL(k3, dim3(4, 5, 16), dim3(512), 0, stream, a2, w3t, b3, a3);
  hipLaunchKernelGGL(k4, dim3(32, 5, 16), dim3(512), 0, stream, a3, w4t, b4, a4);
  hipLaunchKernelGGL(k5, dim3(256), dim3(256), 0, stream, a4, w5, b5, out);
}